// Round 8
// baseline (110.078 us; speedup 1.0000x reference)
//
#include <hip/hip_runtime.h>
#include <stdint.h>

// Problem constants (from reference)
#define DDIM 529                          // 23*23
#define BATCH 2
#define BITS 32
#define HDC 512
#define ROW (BITS * HDC)                  // 16384 floats per bin-row
#define NNZ_REGION (DDIM * HDC)           // 270848 — all indices land here (bb=0, d<=16)
#define SMALL (5 * BATCH * DDIM)          // 5290 small output floats
#define BIN_PER_OUT (BATCH * DDIM * ROW)  // 17334272
#define TOTAL_FLOATS (SMALL + 5 * BIN_PER_OUT)  // 86,676,650
#define Q_BEG 1323                        // first fully-aligned float4 (float 5292)
#define Q_END (TOTAL_FLOATS / 4)          // 21,669,162 -> covers floats [5292, 86676648)

typedef float f32x4 __attribute__((ext_vector_type(4)));

// ---------------------------------------------------------------------------
// Prep: small outputs r,g,b,a,s, their bit-words xw[5290] (row words for the
// stream kernel), plus the 2 unaligned head floats (row 0 / bit 0) and the 2
// tail floats (row 5289 / bit 31). Rewritten every call (ws is poisoned).
// ---------------------------------------------------------------------------
__global__ void prep(const float* __restrict__ data,
                     const float* __restrict__ structure,
                     const float* __restrict__ params,
                     float* __restrict__ out, int* __restrict__ xw) {
    int i = blockIdx.x * blockDim.x + threadIdx.x;
    if (i >= SMALL) return;
    int c = i / 1058, rem = i % 1058, bb = rem / DDIM, d = rem % DDIM;
    float v = (c < 4) ? data[bb * (4 * DDIM) + c * DDIM + d]   // [B][4*23][23]
                      : structure[bb * DDIM + d] * params[d];
    out[i] = v;
    unsigned x = (unsigned)__float_as_int(v);
    xw[i] = (int)x;
    if (i == 0) {                        // head: bins floats 5290,5291 = row 0, bit 0
        float f = (float)(x & 1u);
        out[SMALL] = f; out[SMALL + 1] = f;
    }
    if (i == SMALL - 1) {                // tail: last 2 floats = row 5289, bit 31
        float f = (float)(x >> 31);
        out[TOTAL_FLOATS - 2] = f; out[TOTAL_FLOATS - 1] = f;
    }
}

// ---------------------------------------------------------------------------
// Flat single-frontier stream — IDENTICAL body to R6; only the launch grid
// changes (2048 -> 256 blocks == 1024 waves, fill-like low occupancy).
// ---------------------------------------------------------------------------
__global__ __launch_bounds__(256) void stream4(const int* __restrict__ xw,
                                               float* __restrict__ out) {
    const unsigned nt = gridDim.x * 256u;
    f32x4* o4 = (f32x4*)out;
    for (unsigned q = Q_BEG + blockIdx.x * 256u + threadIdx.x; q < Q_END; q += nt) {
        unsigned E0 = 4u * q - SMALL;          // bins element index, == 2 mod 4
        unsigned E2 = E0 + 2u;
        unsigned w0 = (unsigned)xw[E0 >> 14];  // L1-broadcast (wave-uniform mostly)
        unsigned w1 = (unsigned)xw[E2 >> 14];
        float fa = (float)((w0 >> ((E0 & 16383u) >> 9)) & 1u);
        float fb = (float)((w1 >> ((E2 & 16383u) >> 9)) & 1u);
        f32x4 v = {fa, fa, fb, fb};
        o4[q] = v;
    }
}

// ---------------------------------------------------------------------------
// Sparse fixup: for each nonzero index p (bb=0 frame, p < NNZ_REGION), the
// reference sets proj=1 -> overwrite with bit^1 for all 5 channels.
// Duplicates idempotent. ~5.4 MB of touched lines.
// ---------------------------------------------------------------------------
__global__ void bins_fixup(const int* __restrict__ idx, int n,
                           const int* __restrict__ xw,
                           float* __restrict__ out) {
    int i = blockIdx.x * blockDim.x + threadIdx.x;
    if (i >= n) return;
    unsigned p = (unsigned)idx[i];
    if (p >= NNZ_REGION) return;
    unsigned d = p >> 14;          // row-d (0..16), bb=0
    unsigned j = (p >> 9) & 31u;   // bit index
    #pragma unroll
    for (int c = 0; c < 5; ++c) {
        unsigned w = (unsigned)xw[c * 1058 + d];   // (c, bb=0, d)
        out[(size_t)SMALL + (size_t)c * BIN_PER_OUT + p] = (float)(((w >> j) & 1u) ^ 1u);
    }
}

extern "C" void kernel_launch(void* const* d_in, const int* in_sizes, int n_in,
                              void* d_out, int out_size, void* d_ws, size_t ws_size,
                              hipStream_t stream) {
    const float* data      = (const float*)d_in[0];
    const float* structure = (const float*)d_in[1];
    const float* params    = (const float*)d_in[2];
    const int*   nzi       = (const int*)d_in[3];
    int nnz = in_sizes[3];

    float* out = (float*)d_out;
    int*   xw  = (int*)d_ws;      // 5290 int32 scratch

    prep<<<(SMALL + 255) / 256, 256, 0, stream>>>(data, structure, params, out, xw);
    stream4<<<256, 256, 0, stream>>>(xw, out);   // A/B vs R6: 2048 -> 256 blocks
    bins_fixup<<<(nnz + 255) / 256, 256, 0, stream>>>(nzi, nnz, xw, out);
}

// Round 9
// 87.575 us; speedup vs baseline: 1.2570x; 1.2570x over previous
//
#include <hip/hip_runtime.h>
#include <stdint.h>

// Problem constants (from reference)
#define DDIM 529                          // 23*23
#define BATCH 2
#define BITS 32
#define HDC 512
#define ROW (BITS * HDC)                  // 16384 floats per bin-row
#define NNZ_REGION (DDIM * HDC)           // 270848 — all indices land here (bb=0, d<=16)
#define SMALL (5 * BATCH * DDIM)          // 5290 small output floats (even -> 8B align)
#define BIN_PER_OUT (BATCH * DDIM * ROW)  // 17334272
#define TOTAL_FLOATS (SMALL + 5 * BIN_PER_OUT)  // 86,676,650
#define NCHUNK (5 * BIN_PER_OUT / 512)    // 169,280 value-uniform 512-float chunks

// ---------------------------------------------------------------------------
// Prep: small outputs r,g,b,a,s and their bit-words xw[5290].
// (Chunks cover the bins region exactly — no head/tail specials anymore.)
// ---------------------------------------------------------------------------
__global__ void prep(const float* __restrict__ data,
                     const float* __restrict__ structure,
                     const float* __restrict__ params,
                     float* __restrict__ out, int* __restrict__ xw) {
    int i = blockIdx.x * blockDim.x + threadIdx.x;
    if (i >= SMALL) return;
    int c = i / 1058, rem = i % 1058, bb = rem / DDIM, d = rem % DDIM;
    float v = (c < 4) ? data[bb * (4 * DDIM) + c * DDIM + d]   // [B][4*23][23]
                      : structure[bb * DDIM + d] * params[d];
    out[i] = v;
    xw[i]  = __float_as_int(v);
}

// ---------------------------------------------------------------------------
// Chunk stream: one 512-float value-uniform chunk per wave-iteration.
// chunk k: row r = k>>5 (32 chunks/row), bit j = k&31; value = bit_j(xw[r]).
// Wave writes 2KB as 4 back-to-back float2 stores (offsets fold to immediates).
// All addresses 8B-aligned; chunks tile the bins region exactly.
// ---------------------------------------------------------------------------
__global__ __launch_bounds__(256) void stream_chunks(const int* __restrict__ xw,
                                                     float* __restrict__ out) {
    const unsigned nwaves = (gridDim.x * 256u) >> 6;
    const unsigned wid    = (blockIdx.x * 256u + threadIdx.x) >> 6;
    const unsigned lane   = threadIdx.x & 63u;
    float* bins = out + SMALL;
    for (unsigned k = wid; k < NCHUNK; k += nwaves) {
        unsigned w = (unsigned)xw[k >> 5];        // wave-uniform, L1 broadcast
        float f = (float)((w >> (k & 31u)) & 1u);
        float2 v = make_float2(f, f);
        float* p = bins + ((size_t)k << 9) + lane * 2u;
        *(float2*)(p      ) = v;                  // floats [  0..128)
        *(float2*)(p + 128) = v;                  // floats [128..256)
        *(float2*)(p + 256) = v;                  // floats [256..384)
        *(float2*)(p + 384) = v;                  // floats [384..512)
    }
}

// ---------------------------------------------------------------------------
// Sparse fixup: for each nonzero index p (bb=0 frame, p < NNZ_REGION), the
// reference sets proj=1 -> overwrite with bit^1 for all 5 channels.
// Duplicates idempotent. ~5.4 MB of touched lines.
// ---------------------------------------------------------------------------
__global__ void bins_fixup(const int* __restrict__ idx, int n,
                           const int* __restrict__ xw,
                           float* __restrict__ out) {
    int i = blockIdx.x * blockDim.x + threadIdx.x;
    if (i >= n) return;
    unsigned p = (unsigned)idx[i];
    if (p >= NNZ_REGION) return;
    unsigned d = p >> 14;          // row-d (0..16), bb=0
    unsigned j = (p >> 9) & 31u;   // bit index
    #pragma unroll
    for (int c = 0; c < 5; ++c) {
        unsigned w = (unsigned)xw[c * 1058 + d];   // (c, bb=0, d)
        out[(size_t)SMALL + (size_t)c * BIN_PER_OUT + p] = (float)(((w >> j) & 1u) ^ 1u);
    }
}

extern "C" void kernel_launch(void* const* d_in, const int* in_sizes, int n_in,
                              void* d_out, int out_size, void* d_ws, size_t ws_size,
                              hipStream_t stream) {
    const float* data      = (const float*)d_in[0];
    const float* structure = (const float*)d_in[1];
    const float* params    = (const float*)d_in[2];
    const int*   nzi       = (const int*)d_in[3];
    int nnz = in_sizes[3];

    float* out = (float*)d_out;
    int*   xw  = (int*)d_ws;      // 5290 int32 scratch

    prep<<<(SMALL + 255) / 256, 256, 0, stream>>>(data, structure, params, out, xw);
    stream_chunks<<<2048, 256, 0, stream>>>(xw, out);   // 8192 waves, ~21 chunks each
    bins_fixup<<<(nnz + 255) / 256, 256, 0, stream>>>(nzi, nnz, xw, out);
}

// Round 10
// 80.004 us; speedup vs baseline: 1.3759x; 1.0946x over previous
//
#include <hip/hip_runtime.h>
#include <stdint.h>

// Problem constants (from reference)
#define DDIM 529                          // 23*23
#define BATCH 2
#define BITS 32
#define HDC 512
#define ROW (BITS * HDC)                  // 16384 floats per bin-row
#define NNZ_REGION (DDIM * HDC)           // 270848 — all indices land here (bb=0, d<=16)
#define SMALL (5 * BATCH * DDIM)          // 5290 small output floats
#define BIN_PER_OUT (BATCH * DDIM * ROW)  // 17334272
#define TOTAL_FLOATS (SMALL + 5 * BIN_PER_OUT)  // 86,676,650
#define Q0 1328                           // first float4 ≡ 0 (mod 8) -> 128B-aligned wave spans
#define Q_END (TOTAL_FLOATS / 4)          // 21,669,162 (exclusive)

typedef float f32x4 __attribute__((ext_vector_type(4)));

// ---------------------------------------------------------------------------
// Prep: small outputs + xw[5290] bit-words + head patch (floats 5290..5311,
// all row 0 / bit 0 — elements 0..21 of 512-chunk 0) + tail 2 floats
// (row 5289, bit 31). Stream hot range is then exactly [Q0*4, Q_END*4).
// ---------------------------------------------------------------------------
__global__ void prep(const float* __restrict__ data,
                     const float* __restrict__ structure,
                     const float* __restrict__ params,
                     float* __restrict__ out, int* __restrict__ xw) {
    int i = blockIdx.x * blockDim.x + threadIdx.x;
    if (i >= SMALL) return;
    int c = i / 1058, rem = i % 1058, bb = rem / DDIM, d = rem % DDIM;
    float v = (c < 4) ? data[bb * (4 * DDIM) + c * DDIM + d]   // [B][4*23][23]
                      : structure[bb * DDIM + d] * params[d];
    out[i] = v;
    unsigned x = (unsigned)__float_as_int(v);
    xw[i] = (int)x;
    if (i == 0) {                        // head patch: floats 5290..5311 = bit0(row 0)
        float f = (float)(x & 1u);
        #pragma unroll
        for (int e = 0; e < 22; ++e) out[SMALL + e] = f;
    }
    if (i == SMALL - 1) {                // tail: last 2 floats = bit31(row 5289)
        float f = (float)(x >> 31);
        out[TOTAL_FLOATS - 2] = f; out[TOTAL_FLOATS - 1] = f;
    }
}

// ---------------------------------------------------------------------------
// Flat stream — IDENTICAL body to R6 except the range starts at Q0=1328, so
// every wave's 64x16B span is 128B-aligned (full cache lines only; no
// cross-XCD partial-line RMW). Per-iter bounds check covers the ragged tail.
// ---------------------------------------------------------------------------
__global__ __launch_bounds__(256) void stream4(const int* __restrict__ xw,
                                               float* __restrict__ out) {
    const unsigned nt = gridDim.x * 256u;
    f32x4* o4 = (f32x4*)out;
    for (unsigned q = Q0 + blockIdx.x * 256u + threadIdx.x; q < Q_END; q += nt) {
        unsigned E0 = 4u * q - SMALL;          // bins element index, == 2 mod 4
        unsigned E2 = E0 + 2u;
        unsigned w0 = (unsigned)xw[E0 >> 14];  // L1-broadcast (wave-uniform mostly)
        unsigned w1 = (unsigned)xw[E2 >> 14];
        float fa = (float)((w0 >> ((E0 & 16383u) >> 9)) & 1u);
        float fb = (float)((w1 >> ((E2 & 16383u) >> 9)) & 1u);
        f32x4 v = {fa, fa, fb, fb};
        o4[q] = v;
    }
}

// ---------------------------------------------------------------------------
// Sparse fixup: overwrite proj=1 positions with bit^1 for all 5 channels.
// Duplicates idempotent. ~5.4 MB of touched lines.
// ---------------------------------------------------------------------------
__global__ void bins_fixup(const int* __restrict__ idx, int n,
                           const int* __restrict__ xw,
                           float* __restrict__ out) {
    int i = blockIdx.x * blockDim.x + threadIdx.x;
    if (i >= n) return;
    unsigned p = (unsigned)idx[i];
    if (p >= NNZ_REGION) return;
    unsigned d = p >> 14;          // row-d (0..16), bb=0
    unsigned j = (p >> 9) & 31u;   // bit index
    #pragma unroll
    for (int c = 0; c < 5; ++c) {
        unsigned w = (unsigned)xw[c * 1058 + d];   // (c, bb=0, d)
        out[(size_t)SMALL + (size_t)c * BIN_PER_OUT + p] = (float)(((w >> j) & 1u) ^ 1u);
    }
}

extern "C" void kernel_launch(void* const* d_in, const int* in_sizes, int n_in,
                              void* d_out, int out_size, void* d_ws, size_t ws_size,
                              hipStream_t stream) {
    const float* data      = (const float*)d_in[0];
    const float* structure = (const float*)d_in[1];
    const float* params    = (const float*)d_in[2];
    const int*   nzi       = (const int*)d_in[3];
    int nnz = in_sizes[3];

    float* out = (float*)d_out;
    int*   xw  = (int*)d_ws;      // 5290 int32 scratch

    prep<<<(SMALL + 255) / 256, 256, 0, stream>>>(data, structure, params, out, xw);
    stream4<<<2048, 256, 0, stream>>>(xw, out);   // A/B vs R6: aligned wave spans
    bins_fixup<<<(nnz + 255) / 256, 256, 0, stream>>>(nzi, nnz, xw, out);
}

// Round 12
// 78.311 us; speedup vs baseline: 1.4057x; 1.0216x over previous
//
#include <hip/hip_runtime.h>
#include <stdint.h>

// Problem constants (from reference)
#define DDIM 529                          // 23*23
#define BATCH 2
#define BITS 32
#define HDC 512
#define NNZ_REGION (DDIM * HDC)           // 270848 — all indices land here (bb=0, d<=16)
#define SMALL (5 * BATCH * DDIM)          // 5290 small output floats
#define BIN_PER_OUT (BATCH * DDIM * 16384)// 17334272
#define TOTAL_FLOATS (SMALL + 5 * BIN_PER_OUT)  // 86,676,650
#define Q0 1328                           // first float4 ≡ 0 (mod 8) -> 128B wave spans
#define Q_END (TOTAL_FLOATS / 4)          // 21,669,162 (exclusive); 4*Q0 = float 5312
#define LQ 10584                          // float4s per block (mult of 8); 2048 blocks cover range
#define NBLK 2048

typedef float f32x4 __attribute__((ext_vector_type(4)));

// bit-word of flat row r (r = c*1058 + bb*529 + d) from the tiny L1-resident inputs
__device__ __forceinline__ unsigned rowword(int r,
                                            const float* __restrict__ data,
                                            const float* __restrict__ structure,
                                            const float* __restrict__ params) {
    int c   = r / (BATCH * DDIM);
    int rem = r - c * (BATCH * DDIM);
    int bb  = rem / DDIM;
    int d   = rem - bb * DDIM;
    float v = (c < 4) ? data[bb * (4 * DDIM) + c * DDIM + d]
                      : structure[bb * DDIM + d] * params[d];
    return (unsigned)__float_as_int(v);
}

// ---------------------------------------------------------------------------
// Node 1: contiguous-range stream. Block b owns q in [Q0+b*LQ, min(+LQ,Q_END)),
// spanning <=4 bin-rows; 4 threads compute those row words once into LDS and
// emit the small outputs for owned rows (duplicate writes are identical).
// Block 0 additionally patches the unaligned head (floats 5290..5311, all
// row0/bit0) and the 2-float tail — HERE, not in finalize, so the sparse
// fixup (next kernel) is strictly ordered after them (R11's replay race fix).
// ---------------------------------------------------------------------------
__global__ __launch_bounds__(256) void stream4(const float* __restrict__ data,
                                               const float* __restrict__ structure,
                                               const float* __restrict__ params,
                                               float* __restrict__ out) {
    __shared__ int wds[4];
    const unsigned qa = Q0 + blockIdx.x * LQ;
    const unsigned qe = min(qa + LQ, (unsigned)Q_END);
    const int r_lo = (int)((4u * qa - SMALL) >> 14);
    const int t = threadIdx.x;
    if (t < 4) {
        int r = r_lo + t;
        unsigned w = 0u;
        if (r < SMALL) {
            w = rowword(r, data, structure, params);
            out[r] = __int_as_float((int)w);   // small output (same scalar)
        }
        wds[t] = (int)w;
    } else if (blockIdx.x == 0) {
        if (t >= 32 && t < 54) {               // head: floats 5290..5311 = bit0(row 0)
            unsigned w0 = rowword(0, data, structure, params);
            out[SMALL + (t - 32)] = (float)(w0 & 1u);
        } else if (t == 54) {                  // tail: last 2 floats = bit31(row 5289)
            unsigned w = rowword(SMALL - 1, data, structure, params);
            float f = (float)(w >> 31);
            out[TOTAL_FLOATS - 2] = f; out[TOTAL_FLOATS - 1] = f;
        }
    }
    __syncthreads();

    f32x4* o4 = (f32x4*)out;
    for (unsigned q = qa + t; q < qe; q += 256u) {
        unsigned E0 = 4u * q - SMALL;          // bins element index, == 2 mod 4
        unsigned E2 = E0 + 2u;
        unsigned w0 = (unsigned)wds[(E0 >> 14) - r_lo];   // LDS broadcast
        unsigned w1 = (unsigned)wds[(E2 >> 14) - r_lo];
        float fa = (float)((w0 >> ((E0 & 16383u) >> 9)) & 1u);
        float fb = (float)((w1 >> ((E2 & 16383u) >> 9)) & 1u);
        f32x4 v = {fa, fa, fb, fb};
        o4[q] = v;
    }
}

// ---------------------------------------------------------------------------
// Node 2: pure sparse fixup. For each nonzero index p (bb=0 frame, p <
// NNZ_REGION), reference sets proj=1 -> overwrite with bit^1 for all 5
// channels. Runs strictly after stream4 -> wins over pattern/head writes.
// Duplicates idempotent.
// ---------------------------------------------------------------------------
__global__ __launch_bounds__(256) void finalize(const int* __restrict__ idx, int n,
                                                const float* __restrict__ data,
                                                const float* __restrict__ structure,
                                                const float* __restrict__ params,
                                                float* __restrict__ out) {
    int i = blockIdx.x * blockDim.x + threadIdx.x;
    if (i >= n) return;
    unsigned p = (unsigned)idx[i];
    if (p >= NNZ_REGION) return;
    unsigned d = p >> 14;          // row-d (0..16), bb=0
    unsigned j = (p >> 9) & 31u;   // bit index
    #pragma unroll
    for (int c = 0; c < 5; ++c) {
        float v = (c < 4) ? data[c * DDIM + d] : structure[d] * params[d];
        unsigned bit = ((unsigned)__float_as_int(v) >> j) & 1u;
        out[(size_t)SMALL + (size_t)c * BIN_PER_OUT + p] = (float)(bit ^ 1u);
    }
}

extern "C" void kernel_launch(void* const* d_in, const int* in_sizes, int n_in,
                              void* d_out, int out_size, void* d_ws, size_t ws_size,
                              hipStream_t stream) {
    const float* data      = (const float*)d_in[0];
    const float* structure = (const float*)d_in[1];
    const float* params    = (const float*)d_in[2];
    const int*   nzi       = (const int*)d_in[3];
    int nnz = in_sizes[3];

    float* out = (float*)d_out;

    stream4<<<NBLK, 256, 0, stream>>>(data, structure, params, out);
    finalize<<<(nnz + 255) / 256, 256, 0, stream>>>(nzi, nnz, data, structure, params, out);
}

// Round 14
// 76.307 us; speedup vs baseline: 1.4426x; 1.0263x over previous
//
#include <hip/hip_runtime.h>
#include <stdint.h>

// Problem constants (from reference)
#define DDIM 529                          // 23*23
#define BATCH 2
#define BITS 32
#define HDC 512
#define NNZ_REGION (DDIM * HDC)           // 270848 — all indices land here (bb=0, d<=16)
#define SMALL (5 * BATCH * DDIM)          // 5290 small output floats
#define BIN_PER_OUT (BATCH * DDIM * 16384)// 17334272
#define TOTAL_FLOATS (SMALL + 5 * BIN_PER_OUT)  // 86,676,650
#define Q0 1328                           // first float4 ≡ 0 (mod 8) -> 128B wave spans
#define Q_END (TOTAL_FLOATS / 4)          // 21,669,162 (exclusive); 4*Q0 = float 5312
#define LQ 10584                          // float4s per block (mult of 8); 2048 blocks cover range
#define NBLK 2048

typedef float f32x4 __attribute__((ext_vector_type(4)));

// bit-word of flat row r (r = c*1058 + bb*529 + d) from the tiny L1-resident inputs
__device__ __forceinline__ unsigned rowword(int r,
                                            const float* __restrict__ data,
                                            const float* __restrict__ structure,
                                            const float* __restrict__ params) {
    int c   = r / (BATCH * DDIM);
    int rem = r - c * (BATCH * DDIM);
    int bb  = rem / DDIM;
    int d   = rem - bb * DDIM;
    float v = (c < 4) ? data[bb * (4 * DDIM) + c * DDIM + d]
                      : structure[bb * DDIM + d] * params[d];
    return (unsigned)__float_as_int(v);
}

// ---------------------------------------------------------------------------
// Node 1: contiguous-range stream (proven R12 structure). Block b owns q in
// [Q0+b*LQ, min(+LQ,Q_END)), spanning <=4 bin-rows; 4 threads compute those
// row words once into LDS and emit the small outputs for owned rows
// (duplicate writes identical). Block 0 patches the unaligned head (floats
// 5290..5311 = row0/bit0) and the 2-float tail — here, not in finalize, so
// the sparse fixup (next kernel) is strictly ordered after them.
// ---------------------------------------------------------------------------
__global__ __launch_bounds__(256) void stream4(const float* __restrict__ data,
                                               const float* __restrict__ structure,
                                               const float* __restrict__ params,
                                               float* __restrict__ out) {
    __shared__ int wds[4];
    const unsigned qa = Q0 + blockIdx.x * LQ;
    const unsigned qe = min(qa + LQ, (unsigned)Q_END);
    const int r_lo = (int)((4u * qa - SMALL) >> 14);
    const int t = threadIdx.x;
    if (t < 4) {
        int r = r_lo + t;
        unsigned w = 0u;
        if (r < SMALL) {
            w = rowword(r, data, structure, params);
            out[r] = __int_as_float((int)w);   // small output (same scalar)
        }
        wds[t] = (int)w;
    } else if (blockIdx.x == 0) {
        if (t >= 32 && t < 54) {               // head: floats 5290..5311 = bit0(row 0)
            unsigned w0 = rowword(0, data, structure, params);
            out[SMALL + (t - 32)] = (float)(w0 & 1u);
        } else if (t == 54) {                  // tail: last 2 floats = bit31(row 5289)
            unsigned w = rowword(SMALL - 1, data, structure, params);
            float f = (float)(w >> 31);
            out[TOTAL_FLOATS - 2] = f; out[TOTAL_FLOATS - 1] = f;
        }
    }
    __syncthreads();

    f32x4* o4 = (f32x4*)out;
    for (unsigned q = qa + t; q < qe; q += 256u) {
        unsigned E0 = 4u * q - SMALL;          // bins element index, == 2 mod 4
        unsigned E2 = E0 + 2u;
        unsigned w0 = (unsigned)wds[(E0 >> 14) - r_lo];   // LDS broadcast
        unsigned w1 = (unsigned)wds[(E2 >> 14) - r_lo];
        float fa = (float)((w0 >> ((E0 & 16383u) >> 9)) & 1u);
        float fb = (float)((w1 >> ((E2 & 16383u) >> 9)) & 1u);
        f32x4 v = {fa, fa, fb, fb};
        o4[q] = v;
    }
}

// ---------------------------------------------------------------------------
// Node 2: pure sparse fixup, strictly ordered after stream4. For each nonzero
// index p (bb=0 frame, p < NNZ_REGION): overwrite with bit^1 for all 5
// channels. Duplicates idempotent.
// ---------------------------------------------------------------------------
__global__ __launch_bounds__(256) void finalize(const int* __restrict__ idx, int n,
                                                const float* __restrict__ data,
                                                const float* __restrict__ structure,
                                                const float* __restrict__ params,
                                                float* __restrict__ out) {
    int i = blockIdx.x * blockDim.x + threadIdx.x;
    if (i >= n) return;
    unsigned p = (unsigned)idx[i];
    if (p >= NNZ_REGION) return;
    unsigned d = p >> 14;          // row-d (0..16), bb=0
    unsigned j = (p >> 9) & 31u;   // bit index
    #pragma unroll
    for (int c = 0; c < 5; ++c) {
        float v = (c < 4) ? data[c * DDIM + d] : structure[d] * params[d];
        unsigned bit = ((unsigned)__float_as_int(v) >> j) & 1u;
        out[(size_t)SMALL + (size_t)c * BIN_PER_OUT + p] = (float)(bit ^ 1u);
    }
}

extern "C" void kernel_launch(void* const* d_in, const int* in_sizes, int n_in,
                              void* d_out, int out_size, void* d_ws, size_t ws_size,
                              hipStream_t stream) {
    const float* data      = (const float*)d_in[0];
    const float* structure = (const float*)d_in[1];
    const float* params    = (const float*)d_in[2];
    const int*   nzi       = (const int*)d_in[3];
    int nnz = in_sizes[3];

    float* out = (float*)d_out;

    stream4<<<NBLK, 256, 0, stream>>>(data, structure, params, out);
    finalize<<<(nnz + 255) / 256, 256, 0, stream>>>(nzi, nnz, data, structure, params, out);
}